// Round 4
// baseline (261.980 us; speedup 1.0000x reference)
//
#include <hip/hip_runtime.h>

// L=1024, B=4, IN=D=256, H=8, HD=32, IN2D=16
// ws: q_bf[1M] k_bf[1M] v_t[1M] (ushort) | o_part[JS*1M] lsum_part[JS*32K] (float)

typedef __attribute__((ext_vector_type(8))) short short8;
typedef __attribute__((ext_vector_type(4))) float f32x4;
typedef unsigned short ushort_t;

__device__ inline unsigned short f2bf(float f) {
  unsigned int u = __float_as_uint(f);
  return (unsigned short)((u + 0x7FFFu + ((u >> 16) & 1u)) >> 16);
}

__global__ __launch_bounds__(256) void qkv_proj(
    const float* __restrict__ s, const float* __restrict__ Wq,
    const float* __restrict__ Wk, const float* __restrict__ Wv,
    ushort_t* __restrict__ q_bf, ushort_t* __restrict__ k_bf, ushort_t* __restrict__ v_t)
{
  __shared__ float s_lds[8][256];
  const int t = threadIdx.x;
  const int b = blockIdx.x >> 7;          // fixed batch per block
  const int l0 = (blockIdx.x & 127) << 3; // 8 consecutive l
  for (int rr = 0; rr < 8; ++rr)
    s_lds[rr][t] = s[((size_t)(((l0 + rr) << 2) + b) << 8) + t];
  __syncthreads();
  float aq[8], ak[8], av[8];
#pragma unroll
  for (int rr = 0; rr < 8; ++rr) { aq[rr] = 0.f; ak[rr] = 0.f; av[rr] = 0.f; }
  for (int k = 0; k < 256; ++k) {
    const float wq = Wq[k * 256 + t];
    const float wk = Wk[k * 256 + t];
    const float wv = Wv[k * 256 + t];
#pragma unroll
    for (int rr = 0; rr < 8; ++rr) {
      const float sv = s_lds[rr][k];
      aq[rr] = fmaf(sv, wq, aq[rr]);
      ak[rr] = fmaf(sv, wk, ak[rr]);
      av[rr] = fmaf(sv, wv, av[rr]);
    }
  }
  const int h = t >> 5, dl = t & 31;
#pragma unroll
  for (int rr = 0; rr < 8; ++rr) {
    const int l = l0 + rr;
    q_bf[(((size_t)(b << 10) + l) << 8) + t] = f2bf(aq[rr] * 0.0625f);
    k_bf[((((size_t)((b << 3) + h) << 10) + l) << 5) + dl] = f2bf(ak[rr]);
  }
  short8 vv;
#pragma unroll
  for (int rr = 0; rr < 8; ++rr) vv[rr] = (short)f2bf(av[rr]);
  *(short8*)&v_t[((((size_t)((b << 3) + h) << 5) + dl) << 10) + l0] = vv;
}

__global__ __launch_bounds__(256, 3) void attn_mfma(
    const ushort_t* __restrict__ q_bf, const ushort_t* __restrict__ k_bf,
    const ushort_t* __restrict__ v_t, const float* __restrict__ p,
    const float* __restrict__ W2d, const float* __restrict__ b2d,
    float* __restrict__ o_part, float* __restrict__ lsum_part, int JS)
{
  __shared__ __align__(16) ushort_t p_lds[8][16][40];  // bf16 P (wave-local use only)

  const int t = threadIdx.x;
  const int b = blockIdx.y;
  const int i0 = blockIdx.x << 4;
  const int js = blockIdx.z;
  const int w = t >> 6;      // wave -> heads 2w, 2w+1
  const int l = t & 63;
  const int lrow = l & 15;
  const int lgrp = l >> 4;

  // wave-uniform W2d/b2d into scalar regs
  const int hw = __builtin_amdgcn_readfirstlane(w << 1);
  float w2c[2][16], b2[2];
#pragma unroll
  for (int h2 = 0; h2 < 2; ++h2) {
    b2[h2] = b2d[hw + h2];
#pragma unroll
    for (int c = 0; c < 16; ++c) w2c[h2][c] = W2d[(hw + h2) * 16 + c];
  }

  short8 qa[2];
#pragma unroll
  for (int h2 = 0; h2 < 2; ++h2) {
    const int h = (w << 1) + h2;
    qa[h2] = *(const short8*)&q_bf[(((size_t)(b << 10) + i0 + lrow) << 8) + (h << 5) + (lgrp << 3)];
  }

  f32x4 o_acc[2][2];
  float ls[2][4];
#pragma unroll
  for (int h2 = 0; h2 < 2; ++h2) {
#pragma unroll
    for (int nh = 0; nh < 2; ++nh) o_acc[h2][nh] = (f32x4){0.f, 0.f, 0.f, 0.f};
#pragma unroll
    for (int r = 0; r < 4; ++r) ls[h2][r] = 0.f;
  }

  // per-lane p base: rows i0+4*lgrp+r, col j varies
  const float* pb = p + ((size_t)b << 24) + (((size_t)(i0 + (lgrp << 2))) << 14)
                      + ((size_t)lrow << 4);
  float4 pv[4][4];  // one half-tile (16 j) of bias inputs: 4 i-rows x 16 ch
#define P_ISSUE(jcol)                                                      \
  {                                                                        \
    _Pragma("unroll")                                                      \
    for (int r = 0; r < 4; ++r) {                                          \
      const float4* q4 = (const float4*)(pb + ((size_t)r << 14)            \
                                            + ((size_t)(jcol) << 4));      \
      pv[r][0] = q4[0]; pv[r][1] = q4[1]; pv[r][2] = q4[2]; pv[r][3] = q4[3]; \
    }                                                                      \
  }

#define BIAS(c0)                                                           \
  {                                                                        \
    _Pragma("unroll")                                                      \
    for (int h2 = 0; h2 < 2; ++h2) {                                       \
      _Pragma("unroll")                                                    \
      for (int r = 0; r < 4; ++r) {                                        \
        float a = b2[h2];                                                  \
        a += pv[r][0].x * w2c[h2][0] + pv[r][0].y * w2c[h2][1]             \
           + pv[r][0].z * w2c[h2][2] + pv[r][0].w * w2c[h2][3];            \
        a += pv[r][1].x * w2c[h2][4] + pv[r][1].y * w2c[h2][5]             \
           + pv[r][1].z * w2c[h2][6] + pv[r][1].w * w2c[h2][7];            \
        a += pv[r][2].x * w2c[h2][8] + pv[r][2].y * w2c[h2][9]             \
           + pv[r][2].z * w2c[h2][10] + pv[r][2].w * w2c[h2][11];          \
        a += pv[r][3].x * w2c[h2][12] + pv[r][3].y * w2c[h2][13]           \
           + pv[r][3].z * w2c[h2][14] + pv[r][3].w * w2c[h2][15];          \
        c0[h2][r] = a;                                                     \
      }                                                                    \
    }                                                                      \
  }

#define SCORES(jh, c0)                                                     \
  {                                                                        \
    _Pragma("unroll")                                                      \
    for (int h2 = 0; h2 < 2; ++h2) {                                       \
      const int h = (w << 1) + h2;                                         \
      const int j = j0 + ((jh) << 4) + lrow;                               \
      const short8 kb = *(const short8*)&k_bf[((((size_t)((b << 3) + h) << 10) + j) << 5) + (lgrp << 3)]; \
      f32x4 cc;                                                            \
      _Pragma("unroll")                                                    \
      for (int r = 0; r < 4; ++r) cc[r] = c0[h2][r];                       \
      f32x4 d = __builtin_amdgcn_mfma_f32_16x16x32_bf16(qa[h2], kb, cc, 0, 0, 0); \
      _Pragma("unroll")                                                    \
      for (int r = 0; r < 4; ++r) {                                        \
        const float ex = __expf(d[r]);                                     \
        ls[h2][r] += ex;                                                   \
        p_lds[h][(lgrp << 2) + r][((jh) << 4) + lrow] = f2bf(ex);          \
      }                                                                    \
    }                                                                      \
  }

  const int chunk = 1024 / JS;
  const int jbeg = js * chunk, jend = jbeg + chunk;
  P_ISSUE(jbeg);

  for (int j0 = jbeg; j0 < jend; j0 += 32) {
    float c0[2][4], c1[2][4];
    // half 0
    BIAS(c0);
    P_ISSUE(j0 + 16);          // half 1 (always in range)
    SCORES(0, c0);
    // half 1
    BIAS(c1);
    if (j0 + 32 < jend) P_ISSUE(j0 + 32);
    SCORES(1, c1);
    // PV over the full 32-j tile (wave-local LDS, no barrier needed)
#pragma unroll
    for (int h2 = 0; h2 < 2; ++h2) {
      const int h = (w << 1) + h2;
      const short8 pa = *(const short8*)&p_lds[h][lrow][lgrp << 3];
#pragma unroll
      for (int nh = 0; nh < 2; ++nh) {
        const short8 vb = *(const short8*)&v_t[((((size_t)((b << 3) + h) << 5) + (nh << 4) + lrow) << 10) + j0 + (lgrp << 3)];
        o_acc[h2][nh] = __builtin_amdgcn_mfma_f32_16x16x32_bf16(pa, vb, o_acc[h2][nh], 0, 0, 0);
      }
    }
  }

  // ---- epilogue ----
#pragma unroll
  for (int h2 = 0; h2 < 2; ++h2) {
#pragma unroll
    for (int r = 0; r < 4; ++r) {
      float v = ls[h2][r];
      v += __shfl_xor(v, 1, 16);
      v += __shfl_xor(v, 2, 16);
      v += __shfl_xor(v, 4, 16);
      v += __shfl_xor(v, 8, 16);
      ls[h2][r] = v;
    }
  }
  const size_t obase = ((size_t)js << 20) + (((size_t)(b << 10) + i0) << 8);
#pragma unroll
  for (int h2 = 0; h2 < 2; ++h2) {
    const int h = (w << 1) + h2;
#pragma unroll
    for (int nh = 0; nh < 2; ++nh) {
      const int d = (h << 5) + (nh << 4) + lrow;
#pragma unroll
      for (int r = 0; r < 4; ++r)
        o_part[obase + ((size_t)((lgrp << 2) + r) << 8) + d] = o_acc[h2][nh][r];
    }
  }
  if (lrow == 0) {
#pragma unroll
    for (int h2 = 0; h2 < 2; ++h2) {
      const int h = (w << 1) + h2;
      float* lp = lsum_part + (((size_t)((js << 5) + (b << 3) + h)) << 10) + i0;
#pragma unroll
      for (int r = 0; r < 4; ++r)
        lp[(lgrp << 2) + r] = ls[h2][r];
    }
  }
}

__global__ __launch_bounds__(256) void out_proj(
    const float* __restrict__ o_part, const float* __restrict__ lsum_part,
    const float* __restrict__ Wo, const float* __restrict__ bo,
    float* __restrict__ out, int JS)
{
  __shared__ float o_lds[8][256];
  const int t = threadIdx.x;
  const int r0 = blockIdx.x << 3;
  const int h = t >> 5;
  for (int rr = 0; rr < 8; ++rr) {
    const int r = r0 + rr;
    const int l = r >> 2, bb = r & 3;
    const size_t base = (((size_t)(bb << 10) + l) << 8) + t;
    float acc = 0.f;
    for (int js = 0; js < JS; ++js)
      acc += o_part[((size_t)js << 20) + base];
    float lsv = 0.f;
    for (int js = 0; js < JS; ++js)
      lsv += lsum_part[(((size_t)((js << 5) + (bb << 3) + h)) << 10) + l];
    o_lds[rr][t] = acc / lsv;
  }
  __syncthreads();
  float accs[8];
#pragma unroll
  for (int rr = 0; rr < 8; ++rr) accs[rr] = 0.f;
  for (int k = 0; k < 256; ++k) {
    const float wo = Wo[k * 256 + t];
#pragma unroll
    for (int rr = 0; rr < 8; ++rr)
      accs[rr] = fmaf(o_lds[rr][k], wo, accs[rr]);
  }
  const float bov = bo[t];
#pragma unroll
  for (int rr = 0; rr < 8; ++rr)
    out[(size_t)(r0 + rr) * 256 + t] = accs[rr] + bov;
}

extern "C" void kernel_launch(void* const* d_in, const int* in_sizes, int n_in,
                              void* d_out, int out_size, void* d_ws, size_t ws_size,
                              hipStream_t stream)
{
  const float* s   = (const float*)d_in[0];
  const float* p   = (const float*)d_in[3];
  const float* Wq  = (const float*)d_in[4];
  const float* Wk  = (const float*)d_in[5];
  const float* Wv  = (const float*)d_in[6];
  const float* Wo  = (const float*)d_in[7];
  const float* bo  = (const float*)d_in[8];
  const float* W2d = (const float*)d_in[9];
  const float* b2d = (const float*)d_in[10];
  float* out = (float*)d_out;

  ushort_t* q_bf = (ushort_t*)d_ws;
  ushort_t* k_bf = q_bf + (1 << 20);
  ushort_t* v_t  = k_bf + (1 << 20);
  float* o_part = (float*)(v_t + (1 << 20));

  // bytes: qkv bf16 = 6MB; per js slice: o_part 4MB + lsum 128KB
  int JS = 8;
  {
    const size_t base_b = (size_t)3 * (1 << 20) * 2;
    const size_t per_js = (size_t)(1 << 20) * 4 + (size_t)(1 << 15) * 4;
    while (JS > 1 && base_b + (size_t)JS * per_js > ws_size) JS >>= 1;
  }
  float* lsum_part = o_part + ((size_t)JS << 20);

  qkv_proj<<<dim3(512), dim3(256), 0, stream>>>(s, Wq, Wk, Wv, q_bf, k_bf, v_t);
  attn_mfma<<<dim3(64, 4, JS), dim3(256), 0, stream>>>(q_bf, k_bf, v_t, p, W2d, b2d,
                                                       o_part, lsum_part, JS);
  out_proj<<<dim3(512), dim3(256), 0, stream>>>(o_part, lsum_part, Wo, bo, out, JS);
}

// Round 5
// 208.220 us; speedup vs baseline: 1.2582x; 1.2582x over previous
//
#include <hip/hip_runtime.h>

// L=1024, B=4, IN=D=256, H=8, HD=32, IN2D=16
// ws (2B units): q_bf[1M] k_bf[1M] v_t[1M] | e16[32M halves, layout [b][i][j][h]]
// then (floats): o_part[JS*1M] lsum_part[JS*32K]

typedef __attribute__((ext_vector_type(8))) short short8;
typedef __attribute__((ext_vector_type(4))) float f32x4;
typedef __attribute__((ext_vector_type(8))) _Float16 half8;
typedef __attribute__((ext_vector_type(2))) _Float16 half2_t;
typedef unsigned short ushort_t;

__device__ inline unsigned short f2bf(float f) {
  unsigned int u = __float_as_uint(f);
  return (unsigned short)((u + 0x7FFFu + ((u >> 16) & 1u)) >> 16);
}

__global__ __launch_bounds__(256) void qkv_proj(
    const float* __restrict__ s, const float* __restrict__ Wq,
    const float* __restrict__ Wk, const float* __restrict__ Wv,
    ushort_t* __restrict__ q_bf, ushort_t* __restrict__ k_bf, ushort_t* __restrict__ v_t)
{
  __shared__ float s_lds[8][256];
  const int t = threadIdx.x;
  const int b = blockIdx.x >> 7;          // fixed batch per block
  const int l0 = (blockIdx.x & 127) << 3; // 8 consecutive l
  for (int rr = 0; rr < 8; ++rr)
    s_lds[rr][t] = s[((size_t)(((l0 + rr) << 2) + b) << 8) + t];
  __syncthreads();
  float aq[8], ak[8], av[8];
#pragma unroll
  for (int rr = 0; rr < 8; ++rr) { aq[rr] = 0.f; ak[rr] = 0.f; av[rr] = 0.f; }
  for (int k = 0; k < 256; ++k) {
    const float wq = Wq[k * 256 + t];
    const float wk = Wk[k * 256 + t];
    const float wv = Wv[k * 256 + t];
#pragma unroll
    for (int rr = 0; rr < 8; ++rr) {
      const float sv = s_lds[rr][k];
      aq[rr] = fmaf(sv, wq, aq[rr]);
      ak[rr] = fmaf(sv, wk, ak[rr]);
      av[rr] = fmaf(sv, wv, av[rr]);
    }
  }
  const int h = t >> 5, dl = t & 31;
#pragma unroll
  for (int rr = 0; rr < 8; ++rr) {
    const int l = l0 + rr;
    q_bf[(((size_t)(b << 10) + l) << 8) + t] = f2bf(aq[rr] * 0.0625f);
    k_bf[((((size_t)((b << 3) + h) << 10) + l) << 5) + dl] = f2bf(ak[rr]);
  }
  short8 vv;
#pragma unroll
  for (int rr = 0; rr < 8; ++rr) vv[rr] = (short)f2bf(av[rr]);
  *(short8*)&v_t[((((size_t)((b << 3) + h) << 5) + dl) << 10) + l0] = vv;
}

// bias_mlp: pure streaming. one point (b,i,j) per thread: 64B p in, 16B fp16 out.
__global__ __launch_bounds__(256) void bias_mlp(
    const float* __restrict__ p, const float* __restrict__ W2d,
    const float* __restrict__ b2d, half8* __restrict__ e16)
{
  __shared__ __align__(16) float w2d_s[128];
  __shared__ float b2d_s[8];
  const int t = threadIdx.x;
  if (t < 128) w2d_s[t] = W2d[t];
  if (t < 8) b2d_s[t] = b2d[t];
  __syncthreads();
  const size_t n = ((size_t)blockIdx.x << 8) + t;   // 0 .. 4*1024*1024-1
  const float4* p4 = (const float4*)(p + (n << 4));
  const float4 a = p4[0], b = p4[1], c = p4[2], d = p4[3];
  const float4* w4 = (const float4*)w2d_s;
  half8 r;
#pragma unroll
  for (int h = 0; h < 8; ++h) {
    const float4 w0 = w4[h * 4 + 0], w1 = w4[h * 4 + 1];
    const float4 w2 = w4[h * 4 + 2], w3 = w4[h * 4 + 3];
    float acc = b2d_s[h];
    acc += a.x * w0.x + a.y * w0.y + a.z * w0.z + a.w * w0.w;
    acc += b.x * w1.x + b.y * w1.y + b.z * w1.z + b.w * w1.w;
    acc += c.x * w2.x + c.y * w2.y + c.z * w2.z + c.w * w2.w;
    acc += d.x * w3.x + d.y * w3.y + d.z * w3.z + d.w * w3.w;
    r[h] = (_Float16)acc;
  }
  e16[n] = r;
}

__global__ __launch_bounds__(256) void attn_mfma(
    const ushort_t* __restrict__ q_bf, const ushort_t* __restrict__ k_bf,
    const ushort_t* __restrict__ v_t, const unsigned int* __restrict__ ep,
    float* __restrict__ o_part, float* __restrict__ lsum_part, int JS)
{
  __shared__ __align__(16) ushort_t p_lds[8][16][40];  // bf16 P (wave-local use only)

  const int t = threadIdx.x;
  const int b = blockIdx.y;
  const int i0 = blockIdx.x << 4;
  const int js = blockIdx.z;
  const int w = t >> 6;      // wave -> heads 2w, 2w+1
  const int l = t & 63;
  const int lrow = l & 15;
  const int lgrp = l >> 4;

  short8 qa[2];
#pragma unroll
  for (int h2 = 0; h2 < 2; ++h2) {
    const int h = (w << 1) + h2;
    qa[h2] = *(const short8*)&q_bf[(((size_t)(b << 10) + i0 + lrow) << 8) + (h << 5) + (lgrp << 3)];
  }

  f32x4 o_acc[2][2];
  float ls[2][4];
#pragma unroll
  for (int h2 = 0; h2 < 2; ++h2) {
#pragma unroll
    for (int nh = 0; nh < 2; ++nh) o_acc[h2][nh] = (f32x4){0.f, 0.f, 0.f, 0.f};
#pragma unroll
    for (int r = 0; r < 4; ++r) ls[h2][r] = 0.f;
  }

  // fp16 bias [b][i][j][h]: uint idx = ((b*1024+i)*1024+j)*4 + w  (h-pair per wave)
  const size_t A0 = (((size_t)(b << 10) + i0 + (lgrp << 2)) << 12) + (lrow << 2) + w;

  const int chunk = 1024 / JS;
  const int jbeg = js * chunk, jend = jbeg + chunk;

  for (int j0 = jbeg; j0 < jend; j0 += 32) {
    // ---- Scores: D = Q*K^T + bias(C-operand), exp in-register, P -> bf16 LDS ----
#pragma unroll
    for (int jh = 0; jh < 2; ++jh) {
      unsigned int ub[4];
#pragma unroll
      for (int r = 0; r < 4; ++r)
        ub[r] = ep[A0 + ((size_t)r << 12) + (jh << 6) + ((size_t)j0 << 2)];
#pragma unroll
      for (int h2 = 0; h2 < 2; ++h2) {
        const int h = (w << 1) + h2;
        const int j = j0 + (jh << 4) + lrow;
        const short8 kb = *(const short8*)&k_bf[((((size_t)((b << 3) + h) << 10) + j) << 5) + (lgrp << 3)];
        f32x4 cc;
#pragma unroll
        for (int r = 0; r < 4; ++r) {
          const half2_t hv = __builtin_bit_cast(half2_t, ub[r]);
          cc[r] = (float)hv[h2];
        }
        f32x4 d = __builtin_amdgcn_mfma_f32_16x16x32_bf16(qa[h2], kb, cc, 0, 0, 0);
#pragma unroll
        for (int r = 0; r < 4; ++r) {
          const float ex = __expf(d[r]);
          ls[h2][r] += ex;
          p_lds[h][(lgrp << 2) + r][(jh << 4) + lrow] = f2bf(ex);
        }
      }
    }

    // ---- PV: o += P * V; P from wave-local LDS (A-frag), V transposed bf16 (B-frag) ----
#pragma unroll
    for (int h2 = 0; h2 < 2; ++h2) {
      const int h = (w << 1) + h2;
      const short8 pa = *(const short8*)&p_lds[h][lrow][lgrp << 3];
#pragma unroll
      for (int nh = 0; nh < 2; ++nh) {
        const short8 vb = *(const short8*)&v_t[((((size_t)((b << 3) + h) << 5) + (nh << 4) + lrow) << 10) + j0 + (lgrp << 3)];
        o_acc[h2][nh] = __builtin_amdgcn_mfma_f32_16x16x32_bf16(pa, vb, o_acc[h2][nh], 0, 0, 0);
      }
    }
  }

  // ---- epilogue ----
#pragma unroll
  for (int h2 = 0; h2 < 2; ++h2) {
#pragma unroll
    for (int r = 0; r < 4; ++r) {
      float v = ls[h2][r];
      v += __shfl_xor(v, 1, 16);
      v += __shfl_xor(v, 2, 16);
      v += __shfl_xor(v, 4, 16);
      v += __shfl_xor(v, 8, 16);
      ls[h2][r] = v;
    }
  }
  const size_t obase = ((size_t)js << 20) + (((size_t)(b << 10) + i0) << 8);
#pragma unroll
  for (int h2 = 0; h2 < 2; ++h2) {
    const int h = (w << 1) + h2;
#pragma unroll
    for (int nh = 0; nh < 2; ++nh) {
      const int d = (h << 5) + (nh << 4) + lrow;
#pragma unroll
      for (int r = 0; r < 4; ++r)
        o_part[obase + ((size_t)((lgrp << 2) + r) << 8) + d] = o_acc[h2][nh][r];
    }
  }
  if (lrow == 0) {
#pragma unroll
    for (int h2 = 0; h2 < 2; ++h2) {
      const int h = (w << 1) + h2;
      float* lp = lsum_part + (((size_t)((js << 5) + (b << 3) + h)) << 10) + i0;
#pragma unroll
      for (int r = 0; r < 4; ++r)
        lp[(lgrp << 2) + r] = ls[h2][r];
    }
  }
}

__global__ __launch_bounds__(256) void out_proj(
    const float* __restrict__ o_part, const float* __restrict__ lsum_part,
    const float* __restrict__ Wo, const float* __restrict__ bo,
    float* __restrict__ out, int JS)
{
  __shared__ float o_lds[8][256];
  const int t = threadIdx.x;
  const int r0 = blockIdx.x << 3;
  const int h = t >> 5;
  for (int rr = 0; rr < 8; ++rr) {
    const int r = r0 + rr;
    const int l = r >> 2, bb = r & 3;
    const size_t base = (((size_t)(bb << 10) + l) << 8) + t;
    float acc = 0.f;
    for (int js = 0; js < JS; ++js)
      acc += o_part[((size_t)js << 20) + base];
    float lsv = 0.f;
    for (int js = 0; js < JS; ++js)
      lsv += lsum_part[(((size_t)((js << 5) + (bb << 3) + h)) << 10) + l];
    o_lds[rr][t] = acc / lsv;
  }
  __syncthreads();
  float accs[8];
#pragma unroll
  for (int rr = 0; rr < 8; ++rr) accs[rr] = 0.f;
  for (int k = 0; k < 256; ++k) {
    const float wo = Wo[k * 256 + t];
#pragma unroll
    for (int rr = 0; rr < 8; ++rr)
      accs[rr] = fmaf(o_lds[rr][k], wo, accs[rr]);
  }
  const float bov = bo[t];
#pragma unroll
  for (int rr = 0; rr < 8; ++rr)
    out[(size_t)(r0 + rr) * 256 + t] = accs[rr] + bov;
}

extern "C" void kernel_launch(void* const* d_in, const int* in_sizes, int n_in,
                              void* d_out, int out_size, void* d_ws, size_t ws_size,
                              hipStream_t stream)
{
  const float* s   = (const float*)d_in[0];
  const float* p   = (const float*)d_in[3];
  const float* Wq  = (const float*)d_in[4];
  const float* Wk  = (const float*)d_in[5];
  const float* Wv  = (const float*)d_in[6];
  const float* Wo  = (const float*)d_in[7];
  const float* bo  = (const float*)d_in[8];
  const float* W2d = (const float*)d_in[9];
  const float* b2d = (const float*)d_in[10];
  float* out = (float*)d_out;

  ushort_t* q_bf = (ushort_t*)d_ws;
  ushort_t* k_bf = q_bf + (1 << 20);
  ushort_t* v_t  = k_bf + (1 << 20);
  half8* e16 = (half8*)(v_t + (1 << 20));            // 4M points * 16B = 64MiB
  float* o_part = (float*)((char*)e16 + ((size_t)1 << 26));

  // bytes: qkv bf16 6MiB + e16 64MiB; per js slice: o_part 4MiB + lsum 128KiB
  int JS = 8;
  {
    const size_t base_b = (size_t)6 * (1 << 20) + ((size_t)1 << 26);
    const size_t per_js = (size_t)(1 << 20) * 4 + (size_t)(1 << 15) * 4;
    while (JS > 1 && base_b + (size_t)JS * per_js > ws_size) JS >>= 1;
  }
  float* lsum_part = o_part + ((size_t)JS << 20);

  qkv_proj<<<dim3(512), dim3(256), 0, stream>>>(s, Wq, Wk, Wv, q_bf, k_bf, v_t);
  bias_mlp<<<dim3(16384), dim3(256), 0, stream>>>(p, W2d, b2d, e16);
  attn_mfma<<<dim3(64, 4, JS), dim3(256), 0, stream>>>(q_bf, k_bf, v_t,
                                                       (const unsigned int*)e16,
                                                       o_part, lsum_part, JS);
  out_proj<<<dim3(512), dim3(256), 0, stream>>>(o_part, lsum_part, Wo, bo, out, JS);
}

// Round 6
// 207.782 us; speedup vs baseline: 1.2608x; 1.0021x over previous
//
#include <hip/hip_runtime.h>

// L=1024, B=4, IN=D=256, H=8, HD=32, IN2D=16
// ws (2B units): q_bf[1M] k_bf[1M] v_t[1M] | e16[32M halves, layout [b][i][j][h]]
// then (floats): o_part[JS*1M] lsum_part[JS*32K]

typedef __attribute__((ext_vector_type(8))) short short8;
typedef __attribute__((ext_vector_type(4))) float f32x4;
typedef __attribute__((ext_vector_type(8))) _Float16 half8;
typedef __attribute__((ext_vector_type(2))) _Float16 half2_t;
typedef unsigned short ushort_t;

#define JS_FIXED 4

__device__ inline unsigned short f2bf(float f) {
  unsigned int u = __float_as_uint(f);
  return (unsigned short)((u + 0x7FFFu + ((u >> 16) & 1u)) >> 16);
}

__global__ __launch_bounds__(256) void qkv_proj(
    const float* __restrict__ s, const float* __restrict__ Wq,
    const float* __restrict__ Wk, const float* __restrict__ Wv,
    ushort_t* __restrict__ q_bf, ushort_t* __restrict__ k_bf, ushort_t* __restrict__ v_t)
{
  __shared__ float s_lds[8][256];
  const int t = threadIdx.x;
  const int b = blockIdx.x >> 7;          // fixed batch per block
  const int l0 = (blockIdx.x & 127) << 3; // 8 consecutive l
  for (int rr = 0; rr < 8; ++rr)
    s_lds[rr][t] = s[((size_t)(((l0 + rr) << 2) + b) << 8) + t];
  __syncthreads();
  float aq[8], ak[8], av[8];
#pragma unroll
  for (int rr = 0; rr < 8; ++rr) { aq[rr] = 0.f; ak[rr] = 0.f; av[rr] = 0.f; }
  for (int k = 0; k < 256; ++k) {
    const float wq = Wq[k * 256 + t];
    const float wk = Wk[k * 256 + t];
    const float wv = Wv[k * 256 + t];
#pragma unroll
    for (int rr = 0; rr < 8; ++rr) {
      const float sv = s_lds[rr][k];
      aq[rr] = fmaf(sv, wq, aq[rr]);
      ak[rr] = fmaf(sv, wk, ak[rr]);
      av[rr] = fmaf(sv, wv, av[rr]);
    }
  }
  const int h = t >> 5, dl = t & 31;
#pragma unroll
  for (int rr = 0; rr < 8; ++rr) {
    const int l = l0 + rr;
    q_bf[(((size_t)(b << 10) + l) << 8) + t] = f2bf(aq[rr] * 0.0625f);
    k_bf[((((size_t)((b << 3) + h) << 10) + l) << 5) + dl] = f2bf(ak[rr]);
  }
  short8 vv;
#pragma unroll
  for (int rr = 0; rr < 8; ++rr) vv[rr] = (short)f2bf(av[rr]);
  *(short8*)&v_t[((((size_t)((b << 3) + h) << 5) + dl) << 10) + l0] = vv;
}

// bias_mlp: pure streaming. one point (b,i,j) per thread: 64B p in, 16B fp16 out.
__global__ __launch_bounds__(256) void bias_mlp(
    const float* __restrict__ p, const float* __restrict__ W2d,
    const float* __restrict__ b2d, half8* __restrict__ e16)
{
  __shared__ __align__(16) float w2d_s[128];
  __shared__ float b2d_s[8];
  const int t = threadIdx.x;
  if (t < 128) w2d_s[t] = W2d[t];
  if (t < 8) b2d_s[t] = b2d[t];
  __syncthreads();
  const size_t n = ((size_t)blockIdx.x << 8) + t;   // 0 .. 4*1024*1024-1
  const float4* p4 = (const float4*)(p + (n << 4));
  const float4 a = p4[0], b = p4[1], c = p4[2], d = p4[3];
  const float4* w4 = (const float4*)w2d_s;
  half8 r;
#pragma unroll
  for (int h = 0; h < 8; ++h) {
    const float4 w0 = w4[h * 4 + 0], w1 = w4[h * 4 + 1];
    const float4 w2 = w4[h * 4 + 2], w3 = w4[h * 4 + 3];
    float acc = b2d_s[h];
    acc += a.x * w0.x + a.y * w0.y + a.z * w0.z + a.w * w0.w;
    acc += b.x * w1.x + b.y * w1.y + b.z * w1.z + b.w * w1.w;
    acc += c.x * w2.x + c.y * w2.y + c.z * w2.z + c.w * w2.w;
    acc += d.x * w3.x + d.y * w3.y + d.z * w3.z + d.w * w3.w;
    r[h] = (_Float16)acc;
  }
  e16[n] = r;
}

template <int JS>
__global__ __launch_bounds__(256, 4) void attn_mfma(
    const ushort_t* __restrict__ q_bf, const ushort_t* __restrict__ k_bf,
    const ushort_t* __restrict__ v_t, const unsigned int* __restrict__ ep,
    float* __restrict__ o_part, float* __restrict__ lsum_part)
{
  __shared__ __align__(16) ushort_t p_lds[2][8][16][40];  // parity double-buffered

  const int t = threadIdx.x;
  const int b = blockIdx.y;
  const int i0 = blockIdx.x << 4;
  const int js = blockIdx.z;
  const int w = t >> 6;      // wave -> heads 2w, 2w+1
  const int l = t & 63;
  const int lrow = l & 15;
  const int lgrp = l >> 4;

  short8 qa[2];
#pragma unroll
  for (int h2 = 0; h2 < 2; ++h2) {
    const int h = (w << 1) + h2;
    qa[h2] = *(const short8*)&q_bf[(((size_t)(b << 10) + i0 + lrow) << 8) + (h << 5) + (lgrp << 3)];
  }

  f32x4 o_acc[2][2];
  float ls[2][4];
#pragma unroll
  for (int h2 = 0; h2 < 2; ++h2) {
#pragma unroll
    for (int nh = 0; nh < 2; ++nh) o_acc[h2][nh] = (f32x4){0.f, 0.f, 0.f, 0.f};
#pragma unroll
    for (int r = 0; r < 4; ++r) ls[h2][r] = 0.f;
  }

  // fp16 bias [b][i][j][h]: uint idx = ((b*1024+i)*1024+j)*4 + w  (h-pair per wave)
  const size_t A0 = (((size_t)(b << 10) + i0 + (lgrp << 2)) << 12) + (lrow << 2) + w;

  constexpr int CHUNK = 1024 / JS;
  constexpr int NT = CHUNK / 32;
  const int jbeg = js * CHUNK;

#pragma unroll
  for (int tile = 0; tile < NT; ++tile) {
    const int j0 = jbeg + (tile << 5);
    const int pb = tile & 1;

    // ---- issue ALL tile loads up-front (pipelined across unrolled tiles) ----
    unsigned int ub[2][4];
#pragma unroll
    for (int jh = 0; jh < 2; ++jh)
#pragma unroll
      for (int r = 0; r < 4; ++r)
        ub[jh][r] = ep[A0 + ((size_t)r << 12) + (jh << 6) + ((size_t)j0 << 2)];

    short8 kb[2][2], vb[2][2];
#pragma unroll
    for (int h2 = 0; h2 < 2; ++h2) {
      const int h = (w << 1) + h2;
#pragma unroll
      for (int jh = 0; jh < 2; ++jh) {
        const int j = j0 + (jh << 4) + lrow;
        kb[h2][jh] = *(const short8*)&k_bf[((((size_t)((b << 3) + h) << 10) + j) << 5) + (lgrp << 3)];
      }
#pragma unroll
      for (int nh = 0; nh < 2; ++nh)
        vb[h2][nh] = *(const short8*)&v_t[((((size_t)((b << 3) + h) << 5) + (nh << 4) + lrow) << 10) + j0 + (lgrp << 3)];
    }

    // ---- Scores: D = Q*K^T + bias(C), exp in-register, P -> bf16 LDS ----
#pragma unroll
    for (int jh = 0; jh < 2; ++jh) {
#pragma unroll
      for (int h2 = 0; h2 < 2; ++h2) {
        const int h = (w << 1) + h2;
        f32x4 cc;
#pragma unroll
        for (int r = 0; r < 4; ++r) {
          const half2_t hv = __builtin_bit_cast(half2_t, ub[jh][r]);
          cc[r] = (float)hv[h2];
        }
        f32x4 d = __builtin_amdgcn_mfma_f32_16x16x32_bf16(qa[h2], kb[h2][jh], cc, 0, 0, 0);
#pragma unroll
        for (int r = 0; r < 4; ++r) {
          const float ex = __expf(d[r]);
          ls[h2][r] += ex;
          p_lds[pb][h][(lgrp << 2) + r][(jh << 4) + lrow] = f2bf(ex);
        }
      }
    }

    // ---- PV: o += P * V; P from wave-local LDS (A-frag), V (B-frag, preloaded) ----
#pragma unroll
    for (int h2 = 0; h2 < 2; ++h2) {
      const int h = (w << 1) + h2;
      const short8 pa = *(const short8*)&p_lds[pb][h][lrow][lgrp << 3];
#pragma unroll
      for (int nh = 0; nh < 2; ++nh)
        o_acc[h2][nh] = __builtin_amdgcn_mfma_f32_16x16x32_bf16(pa, vb[h2][nh], o_acc[h2][nh], 0, 0, 0);
    }
  }

  // ---- epilogue ----
#pragma unroll
  for (int h2 = 0; h2 < 2; ++h2) {
#pragma unroll
    for (int r = 0; r < 4; ++r) {
      float v = ls[h2][r];
      v += __shfl_xor(v, 1, 16);
      v += __shfl_xor(v, 2, 16);
      v += __shfl_xor(v, 4, 16);
      v += __shfl_xor(v, 8, 16);
      ls[h2][r] = v;
    }
  }
  const size_t obase = ((size_t)js << 20) + (((size_t)(b << 10) + i0) << 8);
#pragma unroll
  for (int h2 = 0; h2 < 2; ++h2) {
    const int h = (w << 1) + h2;
#pragma unroll
    for (int nh = 0; nh < 2; ++nh) {
      const int d = (h << 5) + (nh << 4) + lrow;
#pragma unroll
      for (int r = 0; r < 4; ++r)
        o_part[obase + ((size_t)((lgrp << 2) + r) << 8) + d] = o_acc[h2][nh][r];
    }
  }
  if (lrow == 0) {
#pragma unroll
    for (int h2 = 0; h2 < 2; ++h2) {
      const int h = (w << 1) + h2;
      float* lp = lsum_part + (((size_t)((js << 5) + (b << 3) + h)) << 10) + i0;
#pragma unroll
      for (int r = 0; r < 4; ++r)
        lp[(lgrp << 2) + r] = ls[h2][r];
    }
  }
}

__global__ __launch_bounds__(256) void out_proj(
    const float* __restrict__ o_part, const float* __restrict__ lsum_part,
    const float* __restrict__ Wo, const float* __restrict__ bo,
    float* __restrict__ out)
{
  constexpr int JS = JS_FIXED;
  __shared__ float o_lds[8][256];
  const int t = threadIdx.x;
  const int r0 = blockIdx.x << 3;
  const int h = t >> 5;
  for (int rr = 0; rr < 8; ++rr) {
    const int r = r0 + rr;
    const int l = r >> 2, bb = r & 3;
    const size_t base = (((size_t)(bb << 10) + l) << 8) + t;
    float acc = 0.f;
#pragma unroll
    for (int js = 0; js < JS; ++js)
      acc += o_part[((size_t)js << 20) + base];
    float lsv = 0.f;
#pragma unroll
    for (int js = 0; js < JS; ++js)
      lsv += lsum_part[(((size_t)((js << 5) + (bb << 3) + h)) << 10) + l];
    o_lds[rr][t] = acc / lsv;
  }
  __syncthreads();
  float accs[8];
#pragma unroll
  for (int rr = 0; rr < 8; ++rr) accs[rr] = 0.f;
  for (int k = 0; k < 256; ++k) {
    const float wo = Wo[k * 256 + t];
#pragma unroll
    for (int rr = 0; rr < 8; ++rr)
      accs[rr] = fmaf(o_lds[rr][k], wo, accs[rr]);
  }
  const float bov = bo[t];
#pragma unroll
  for (int rr = 0; rr < 8; ++rr)
    out[(size_t)(r0 + rr) * 256 + t] = accs[rr] + bov;
}

extern "C" void kernel_launch(void* const* d_in, const int* in_sizes, int n_in,
                              void* d_out, int out_size, void* d_ws, size_t ws_size,
                              hipStream_t stream)
{
  const float* s   = (const float*)d_in[0];
  const float* p   = (const float*)d_in[3];
  const float* Wq  = (const float*)d_in[4];
  const float* Wk  = (const float*)d_in[5];
  const float* Wv  = (const float*)d_in[6];
  const float* Wo  = (const float*)d_in[7];
  const float* bo  = (const float*)d_in[8];
  const float* W2d = (const float*)d_in[9];
  const float* b2d = (const float*)d_in[10];
  float* out = (float*)d_out;

  ushort_t* q_bf = (ushort_t*)d_ws;
  ushort_t* k_bf = q_bf + (1 << 20);
  ushort_t* v_t  = k_bf + (1 << 20);
  half8* e16 = (half8*)(v_t + (1 << 20));            // 4M points * 16B = 64MiB
  float* o_part = (float*)((char*)e16 + ((size_t)1 << 26));
  float* lsum_part = o_part + ((size_t)JS_FIXED << 20);
  // total: 6MiB + 64MiB + 16MiB + 0.5MiB = 86.5MiB  (ws is >= 1GiB per harness fill)

  qkv_proj<<<dim3(512), dim3(256), 0, stream>>>(s, Wq, Wk, Wv, q_bf, k_bf, v_t);
  bias_mlp<<<dim3(16384), dim3(256), 0, stream>>>(p, W2d, b2d, e16);
  attn_mfma<JS_FIXED><<<dim3(64, 4, JS_FIXED), dim3(256), 0, stream>>>(
      q_bf, k_bf, v_t, (const unsigned int*)e16, o_part, lsum_part);
  out_proj<<<dim3(512), dim3(256), 0, stream>>>(o_part, lsum_part, Wo, bo, out);
}

// Round 7
// 181.126 us; speedup vs baseline: 1.4464x; 1.1472x over previous
//
#include <hip/hip_runtime.h>

// L=1024, B=4, IN=D=256, H=8, HD=32, IN2D=16
// ws (2B units): q_bf[1M] k_bf[1M] v_t[1M] | e16[32M halves, layout [b][i][j][h]]
// then (floats): o_part[JS*1M] lsum_part[JS*32K]

typedef __attribute__((ext_vector_type(8))) short short8;
typedef __attribute__((ext_vector_type(4))) float f32x4;
typedef __attribute__((ext_vector_type(8))) _Float16 half8;
typedef __attribute__((ext_vector_type(2))) _Float16 half2_t;
typedef unsigned short ushort_t;

#define JS_FIXED 4

__device__ inline unsigned short f2bf(float f) {
  unsigned int u = __float_as_uint(f);
  return (unsigned short)((u + 0x7FFFu + ((u >> 16) & 1u)) >> 16);
}

__global__ __launch_bounds__(256) void qkv_proj(
    const float* __restrict__ s, const float* __restrict__ Wq,
    const float* __restrict__ Wk, const float* __restrict__ Wv,
    ushort_t* __restrict__ q_bf, ushort_t* __restrict__ k_bf, ushort_t* __restrict__ v_t)
{
  __shared__ float s_lds[8][256];
  const int t = threadIdx.x;
  const int b = blockIdx.x >> 7;          // fixed batch per block
  const int l0 = (blockIdx.x & 127) << 3; // 8 consecutive l
  for (int rr = 0; rr < 8; ++rr)
    s_lds[rr][t] = s[((size_t)(((l0 + rr) << 2) + b) << 8) + t];
  __syncthreads();
  float aq[8], ak[8], av[8];
#pragma unroll
  for (int rr = 0; rr < 8; ++rr) { aq[rr] = 0.f; ak[rr] = 0.f; av[rr] = 0.f; }
  for (int k = 0; k < 256; ++k) {
    const float wq = Wq[k * 256 + t];
    const float wk = Wk[k * 256 + t];
    const float wv = Wv[k * 256 + t];
#pragma unroll
    for (int rr = 0; rr < 8; ++rr) {
      const float sv = s_lds[rr][k];
      aq[rr] = fmaf(sv, wq, aq[rr]);
      ak[rr] = fmaf(sv, wk, ak[rr]);
      av[rr] = fmaf(sv, wv, av[rr]);
    }
  }
  const int h = t >> 5, dl = t & 31;
#pragma unroll
  for (int rr = 0; rr < 8; ++rr) {
    const int l = l0 + rr;
    q_bf[(((size_t)(b << 10) + l) << 8) + t] = f2bf(aq[rr] * 0.0625f);
    k_bf[((((size_t)((b << 3) + h) << 10) + l) << 5) + dl] = f2bf(ak[rr]);
  }
  short8 vv;
#pragma unroll
  for (int rr = 0; rr < 8; ++rr) vv[rr] = (short)f2bf(av[rr]);
  *(short8*)&v_t[((((size_t)((b << 3) + h) << 5) + dl) << 10) + l0] = vv;
}

// bias_mlp: pure streaming. one point (b,i,j) per thread: 64B p in, 16B fp16 out.
__global__ __launch_bounds__(256) void bias_mlp(
    const float* __restrict__ p, const float* __restrict__ W2d,
    const float* __restrict__ b2d, half8* __restrict__ e16)
{
  __shared__ __align__(16) float w2d_s[128];
  __shared__ float b2d_s[8];
  const int t = threadIdx.x;
  if (t < 128) w2d_s[t] = W2d[t];
  if (t < 8) b2d_s[t] = b2d[t];
  __syncthreads();
  const size_t n = ((size_t)blockIdx.x << 8) + t;   // 0 .. 4*1024*1024-1
  const float4* p4 = (const float4*)(p + (n << 4));
  const float4 a = p4[0], b = p4[1], c = p4[2], d = p4[3];
  const float4* w4 = (const float4*)w2d_s;
  half8 r;
#pragma unroll
  for (int h = 0; h < 8; ++h) {
    const float4 w0 = w4[h * 4 + 0], w1 = w4[h * 4 + 1];
    const float4 w2 = w4[h * 4 + 2], w3 = w4[h * 4 + 3];
    float acc = b2d_s[h];
    acc += a.x * w0.x + a.y * w0.y + a.z * w0.z + a.w * w0.w;
    acc += b.x * w1.x + b.y * w1.y + b.z * w1.z + b.w * w1.w;
    acc += c.x * w2.x + c.y * w2.y + c.z * w2.z + c.w * w2.w;
    acc += d.x * w3.x + d.y * w3.y + d.z * w3.z + d.w * w3.w;
    r[h] = (_Float16)acc;
  }
  e16[n] = r;
}

template <int JS>
__global__ __launch_bounds__(256, 4) void attn_mfma(
    const ushort_t* __restrict__ q_bf, const ushort_t* __restrict__ k_bf,
    const ushort_t* __restrict__ v_t, const unsigned int* __restrict__ ep,
    float* __restrict__ o_part, float* __restrict__ lsum_part)
{
  __shared__ __align__(16) ushort_t p_lds[2][8][16][40];  // parity double-buffered

  const int t = threadIdx.x;
  // ---- bijective XCD swizzle: each XCD owns 2 (b,js) combos -> K/V fit its L2 ----
  const int flat = blockIdx.x + (blockIdx.y << 6) + (blockIdx.z << 8);  // 0..1023
  const int swz = ((flat & 7) << 7) + (flat >> 3);
  const int i0 = (swz & 63) << 4;
  const int b  = (swz >> 6) & 3;
  const int js = swz >> 8;

  const int w = t >> 6;      // wave -> heads 2w, 2w+1
  const int l = t & 63;
  const int lrow = l & 15;
  const int lgrp = l >> 4;

  short8 qa[2];
#pragma unroll
  for (int h2 = 0; h2 < 2; ++h2) {
    const int h = (w << 1) + h2;
    qa[h2] = *(const short8*)&q_bf[(((size_t)(b << 10) + i0 + lrow) << 8) + (h << 5) + (lgrp << 3)];
  }

  f32x4 o_acc[2][2];
  float ls[2][4];
#pragma unroll
  for (int h2 = 0; h2 < 2; ++h2) {
#pragma unroll
    for (int nh = 0; nh < 2; ++nh) o_acc[h2][nh] = (f32x4){0.f, 0.f, 0.f, 0.f};
#pragma unroll
    for (int r = 0; r < 4; ++r) ls[h2][r] = 0.f;
  }

  // fp16 bias [b][i][j][h]: uint idx = ((b*1024+i)*1024+j)*4 + w  (h-pair per wave)
  const size_t A0 = (((size_t)(b << 10) + i0 + (lgrp << 2)) << 12) + (lrow << 2) + w;

  auto LOADE = [&](int j0, unsigned int (&ub)[2][4]) {
#pragma unroll
    for (int jh = 0; jh < 2; ++jh)
#pragma unroll
      for (int r = 0; r < 4; ++r)
        ub[jh][r] = ep[A0 + ((size_t)r << 12) + (jh << 6) + ((size_t)j0 << 2)];
  };

  auto COMPUTE = [&](int j0, unsigned int (&ub)[2][4], int pb) {
    // ---- Scores: D = Q*K^T + bias(C), exp in-register, P -> bf16 LDS ----
#pragma unroll
    for (int jh = 0; jh < 2; ++jh) {
#pragma unroll
      for (int h2 = 0; h2 < 2; ++h2) {
        const int h = (w << 1) + h2;
        const short8 kb = *(const short8*)&k_bf[((((size_t)((b << 3) + h) << 10) + j0 + (jh << 4) + lrow) << 5) + (lgrp << 3)];
        f32x4 cc;
#pragma unroll
        for (int r = 0; r < 4; ++r) {
          const half2_t hv = __builtin_bit_cast(half2_t, ub[jh][r]);
          cc[r] = (float)hv[h2];
        }
        f32x4 d = __builtin_amdgcn_mfma_f32_16x16x32_bf16(qa[h2], kb, cc, 0, 0, 0);
#pragma unroll
        for (int r = 0; r < 4; ++r) {
          const float ex = __expf(d[r]);
          ls[h2][r] += ex;
          p_lds[pb][h][(lgrp << 2) + r][(jh << 4) + lrow] = f2bf(ex);
        }
      }
    }
    // ---- PV: o += P * V; P from wave-local LDS (A-frag), V JIT from L2 (B-frag) ----
#pragma unroll
    for (int h2 = 0; h2 < 2; ++h2) {
      const int h = (w << 1) + h2;
      const short8 pa = *(const short8*)&p_lds[pb][h][lrow][lgrp << 3];
#pragma unroll
      for (int nh = 0; nh < 2; ++nh) {
        const short8 vb = *(const short8*)&v_t[((((size_t)((b << 3) + h) << 5) + (nh << 4) + lrow) << 10) + j0 + (lgrp << 3)];
        o_acc[h2][nh] = __builtin_amdgcn_mfma_f32_16x16x32_bf16(pa, vb, o_acc[h2][nh], 0, 0, 0);
      }
    }
  };

  constexpr int CHUNK = 1024 / JS;   // 256
  constexpr int NT = CHUNK / 32;     // 8 (even)
  const int jbeg = js * CHUNK;
  const int jlast = jbeg + CHUNK - 32;

  unsigned int ubA[2][4], ubB[2][4];
  LOADE(jbeg, ubA);
#pragma unroll 1
  for (int t2 = 0; t2 < NT; t2 += 2) {
    const int j0 = jbeg + (t2 << 5);
    const int jn1 = (j0 + 32 < jlast) ? (j0 + 32) : jlast;
    const int jn2 = (j0 + 64 < jlast) ? (j0 + 64) : jlast;
    LOADE(jn1, ubB);        // prefetch tile t2+1
    COMPUTE(j0, ubA, 0);
    LOADE(jn2, ubA);        // prefetch tile t2+2
    COMPUTE(j0 + 32, ubB, 1);
  }

  // ---- epilogue ----
#pragma unroll
  for (int h2 = 0; h2 < 2; ++h2) {
#pragma unroll
    for (int r = 0; r < 4; ++r) {
      float v = ls[h2][r];
      v += __shfl_xor(v, 1, 16);
      v += __shfl_xor(v, 2, 16);
      v += __shfl_xor(v, 4, 16);
      v += __shfl_xor(v, 8, 16);
      ls[h2][r] = v;
    }
  }
  const size_t obase = ((size_t)js << 20) + (((size_t)(b << 10) + i0) << 8);
#pragma unroll
  for (int h2 = 0; h2 < 2; ++h2) {
    const int h = (w << 1) + h2;
#pragma unroll
    for (int nh = 0; nh < 2; ++nh) {
      const int d = (h << 5) + (nh << 4) + lrow;
#pragma unroll
      for (int r = 0; r < 4; ++r)
        o_part[obase + ((size_t)((lgrp << 2) + r) << 8) + d] = o_acc[h2][nh][r];
    }
  }
  if (lrow == 0) {
#pragma unroll
    for (int h2 = 0; h2 < 2; ++h2) {
      const int h = (w << 1) + h2;
      float* lp = lsum_part + (((size_t)((js << 5) + (b << 3) + h)) << 10) + i0;
#pragma unroll
      for (int r = 0; r < 4; ++r)
        lp[(lgrp << 2) + r] = ls[h2][r];
    }
  }
}

__global__ __launch_bounds__(256) void out_proj(
    const float* __restrict__ o_part, const float* __restrict__ lsum_part,
    const float* __restrict__ Wo, const float* __restrict__ bo,
    float* __restrict__ out)
{
  constexpr int JS = JS_FIXED;
  __shared__ float o_lds[8][256];
  const int t = threadIdx.x;
  const int r0 = blockIdx.x << 3;
  const int h = t >> 5;
  for (int rr = 0; rr < 8; ++rr) {
    const int r = r0 + rr;
    const int l = r >> 2, bb = r & 3;
    const size_t base = (((size_t)(bb << 10) + l) << 8) + t;
    float acc = 0.f;
#pragma unroll
    for (int js = 0; js < JS; ++js)
      acc += o_part[((size_t)js << 20) + base];
    float lsv = 0.f;
#pragma unroll
    for (int js = 0; js < JS; ++js)
      lsv += lsum_part[(((size_t)((js << 5) + (bb << 3) + h)) << 10) + l];
    o_lds[rr][t] = acc / lsv;
  }
  __syncthreads();
  float accs[8];
#pragma unroll
  for (int rr = 0; rr < 8; ++rr) accs[rr] = 0.f;
  for (int k = 0; k < 256; ++k) {
    const float wo = Wo[k * 256 + t];
#pragma unroll
    for (int rr = 0; rr < 8; ++rr)
      accs[rr] = fmaf(o_lds[rr][k], wo, accs[rr]);
  }
  const float bov = bo[t];
#pragma unroll
  for (int rr = 0; rr < 8; ++rr)
    out[(size_t)(r0 + rr) * 256 + t] = accs[rr] + bov;
}

extern "C" void kernel_launch(void* const* d_in, const int* in_sizes, int n_in,
                              void* d_out, int out_size, void* d_ws, size_t ws_size,
                              hipStream_t stream)
{
  const float* s   = (const float*)d_in[0];
  const float* p   = (const float*)d_in[3];
  const float* Wq  = (const float*)d_in[4];
  const float* Wk  = (const float*)d_in[5];
  const float* Wv  = (const float*)d_in[6];
  const float* Wo  = (const float*)d_in[7];
  const float* bo  = (const float*)d_in[8];
  const float* W2d = (const float*)d_in[9];
  const float* b2d = (const float*)d_in[10];
  float* out = (float*)d_out;

  ushort_t* q_bf = (ushort_t*)d_ws;
  ushort_t* k_bf = q_bf + (1 << 20);
  ushort_t* v_t  = k_bf + (1 << 20);
  half8* e16 = (half8*)(v_t + (1 << 20));            // 4M points * 16B = 64MiB
  float* o_part = (float*)((char*)e16 + ((size_t)1 << 26));
  float* lsum_part = o_part + ((size_t)JS_FIXED << 20);
  // total: 6MiB + 64MiB + 16MiB + 0.5MiB = 86.5MiB

  qkv_proj<<<dim3(512), dim3(256), 0, stream>>>(s, Wq, Wk, Wv, q_bf, k_bf, v_t);
  bias_mlp<<<dim3(16384), dim3(256), 0, stream>>>(p, W2d, b2d, e16);
  attn_mfma<JS_FIXED><<<dim3(64, 4, JS_FIXED), dim3(256), 0, stream>>>(
      q_bf, k_bf, v_t, (const unsigned int*)e16, o_part, lsum_part);
  out_proj<<<dim3(512), dim3(256), 0, stream>>>(o_part, lsum_part, Wo, bo, out);
}

// Round 8
// 143.154 us; speedup vs baseline: 1.8300x; 1.2653x over previous
//
#include <hip/hip_runtime.h>

// L=1024, B=4, IN=D=256, H=8, HD=32, IN2D=16
// ws (2B units): q_bf[1M] k_bf[1M] v_t[1M] | e16[32M halves, layout [b][w][i][j][2]]
// then (floats): o_part[JS*1M] lsum_part[JS*32K]

typedef __attribute__((ext_vector_type(8))) short short8;
typedef __attribute__((ext_vector_type(4))) float f32x4;
typedef __attribute__((ext_vector_type(2))) _Float16 half2_t;
typedef unsigned short ushort_t;

#define JS_FIXED 4

__device__ inline unsigned short f2bf(float f) {
  unsigned int u = __float_as_uint(f);
  return (unsigned short)((u + 0x7FFFu + ((u >> 16) & 1u)) >> 16);
}

// prep: blocks 0..511 do the QKV projection; blocks 512.. do the bias MLP.
// The VALU-bound qkv blocks co-schedule under the BW-bound bias stream.
__global__ __launch_bounds__(256) void prep(
    const float* __restrict__ s, const float* __restrict__ Wq,
    const float* __restrict__ Wk, const float* __restrict__ Wv,
    const float* __restrict__ p, const float* __restrict__ W2d,
    const float* __restrict__ b2d,
    ushort_t* __restrict__ q_bf, ushort_t* __restrict__ k_bf, ushort_t* __restrict__ v_t,
    unsigned int* __restrict__ e16)
{
  __shared__ float s_lds[8][256];
  __shared__ __align__(16) float w2d_s[128];
  __shared__ float b2d_s[8];
  const int t = threadIdx.x;

  if (blockIdx.x < 512) {
    // ---------------- QKV projection ----------------
    const int b = blockIdx.x >> 7;          // fixed batch per block
    const int l0 = (blockIdx.x & 127) << 3; // 8 consecutive l
    for (int rr = 0; rr < 8; ++rr)
      s_lds[rr][t] = s[((size_t)(((l0 + rr) << 2) + b) << 8) + t];
    __syncthreads();
    float aq[8], ak[8], av[8];
#pragma unroll
    for (int rr = 0; rr < 8; ++rr) { aq[rr] = 0.f; ak[rr] = 0.f; av[rr] = 0.f; }
    for (int k = 0; k < 256; ++k) {
      const float wq = Wq[k * 256 + t];
      const float wk = Wk[k * 256 + t];
      const float wv = Wv[k * 256 + t];
#pragma unroll
      for (int rr = 0; rr < 8; ++rr) {
        const float sv = s_lds[rr][k];
        aq[rr] = fmaf(sv, wq, aq[rr]);
        ak[rr] = fmaf(sv, wk, ak[rr]);
        av[rr] = fmaf(sv, wv, av[rr]);
      }
    }
    const int h = t >> 5, dl = t & 31;
#pragma unroll
    for (int rr = 0; rr < 8; ++rr) {
      const int l = l0 + rr;
      q_bf[(((size_t)(b << 10) + l) << 8) + t] = f2bf(aq[rr] * 0.0625f);
      k_bf[((((size_t)((b << 3) + h) << 10) + l) << 5) + dl] = f2bf(ak[rr]);
    }
    short8 vv;
#pragma unroll
    for (int rr = 0; rr < 8; ++rr) vv[rr] = (short)f2bf(av[rr]);
    *(short8*)&v_t[((((size_t)((b << 3) + h) << 5) + dl) << 10) + l0] = vv;
  } else {
    // ---------------- bias MLP (pure streaming) ----------------
    if (t < 128) w2d_s[t] = W2d[t];
    if (t < 8) b2d_s[t] = b2d[t];
    __syncthreads();
    const size_t n = (((size_t)blockIdx.x - 512) << 8) + t;  // 0 .. 4M-1
    const int b = (int)(n >> 20);
    const unsigned int ij = (unsigned int)(n & 0xFFFFFu);
    const float4* p4 = (const float4*)(p + (n << 4));
    const float4 a = p4[0], bb = p4[1], c = p4[2], d = p4[3];
    const float4* w4 = (const float4*)w2d_s;
    float acc[8];
#pragma unroll
    for (int h = 0; h < 8; ++h) {
      const float4 w0 = w4[h * 4 + 0], w1 = w4[h * 4 + 1];
      const float4 w2 = w4[h * 4 + 2], w3 = w4[h * 4 + 3];
      float av = b2d_s[h];
      av += a.x * w0.x + a.y * w0.y + a.z * w0.z + a.w * w0.w;
      av += bb.x * w1.x + bb.y * w1.y + bb.z * w1.z + bb.w * w1.w;
      av += c.x * w2.x + c.y * w2.y + c.z * w2.z + c.w * w2.w;
      av += d.x * w3.x + d.y * w3.y + d.z * w3.z + d.w * w3.w;
      acc[h] = av;
    }
    // per-head-pair planes: e16[((b*4+w)<<20) + ij] = half2(acc[2w], acc[2w+1])
#pragma unroll
    for (int w = 0; w < 4; ++w) {
      half2_t hv;
      hv[0] = (_Float16)acc[2 * w];
      hv[1] = (_Float16)acc[2 * w + 1];
      e16[(((size_t)((b << 2) + w)) << 20) + ij] = __builtin_bit_cast(unsigned int, hv);
    }
  }
}

template <int JS>
__global__ __launch_bounds__(256, 4) void attn_mfma(
    const ushort_t* __restrict__ q_bf, const ushort_t* __restrict__ k_bf,
    const ushort_t* __restrict__ v_t, const unsigned int* __restrict__ ep,
    float* __restrict__ o_part, float* __restrict__ lsum_part)
{
  __shared__ __align__(16) ushort_t p_lds[2][8][16][40];  // parity double-buffered

  const int t = threadIdx.x;
  // ---- bijective XCD swizzle: all js/b of an i-column family share an XCD L2 ----
  const int flat = blockIdx.x + (blockIdx.y << 6) + (blockIdx.z << 8);  // 0..1023
  const int swz = ((flat & 7) << 7) + (flat >> 3);
  const int i0 = (swz & 63) << 4;
  const int b  = (swz >> 6) & 3;
  const int js = swz >> 8;

  const int w = t >> 6;      // wave -> heads 2w, 2w+1
  const int l = t & 63;
  const int lrow = l & 15;
  const int lgrp = l >> 4;

  short8 qa[2];
#pragma unroll
  for (int h2 = 0; h2 < 2; ++h2) {
    const int h = (w << 1) + h2;
    qa[h2] = *(const short8*)&q_bf[(((size_t)(b << 10) + i0 + lrow) << 8) + (h << 5) + (lgrp << 3)];
  }

  f32x4 o_acc[2][2];
  float ls[2][4];
#pragma unroll
  for (int h2 = 0; h2 < 2; ++h2) {
#pragma unroll
    for (int nh = 0; nh < 2; ++nh) o_acc[h2][nh] = (f32x4){0.f, 0.f, 0.f, 0.f};
#pragma unroll
    for (int r = 0; r < 4; ++r) ls[h2][r] = 0.f;
  }

  // e16 plane [b][w]: fully-coalesced reads (lane stride 4B)
  const size_t A0 = (((size_t)((b << 2) + w)) << 20) + ((size_t)(i0 + (lgrp << 2)) << 10) + lrow;

  auto LOADE = [&](int j0, unsigned int (&ub)[2][4]) {
#pragma unroll
    for (int jh = 0; jh < 2; ++jh)
#pragma unroll
      for (int r = 0; r < 4; ++r)
        ub[jh][r] = ep[A0 + ((size_t)r << 10) + (jh << 4) + j0];
  };

  auto COMPUTE = [&](int j0, unsigned int (&ub)[2][4], int pb) {
    // ---- Scores: D = Q*K^T + bias(C), exp in-register, P -> bf16 LDS ----
#pragma unroll
    for (int jh = 0; jh < 2; ++jh) {
#pragma unroll
      for (int h2 = 0; h2 < 2; ++h2) {
        const int h = (w << 1) + h2;
        const short8 kb = *(const short8*)&k_bf[((((size_t)((b << 3) + h) << 10) + j0 + (jh << 4) + lrow) << 5) + (lgrp << 3)];
        f32x4 cc;
#pragma unroll
        for (int r = 0; r < 4; ++r) {
          const half2_t hv = __builtin_bit_cast(half2_t, ub[jh][r]);
          cc[r] = (float)hv[h2];
        }
        f32x4 d = __builtin_amdgcn_mfma_f32_16x16x32_bf16(qa[h2], kb, cc, 0, 0, 0);
#pragma unroll
        for (int r = 0; r < 4; ++r) {
          const float ex = __expf(d[r]);
          ls[h2][r] += ex;
          p_lds[pb][h][(lgrp << 2) + r][(jh << 4) + lrow] = f2bf(ex);
        }
      }
    }
    // ---- PV: o += P * V; P from wave-local LDS (A-frag), V JIT from L2 (B-frag) ----
#pragma unroll
    for (int h2 = 0; h2 < 2; ++h2) {
      const int h = (w << 1) + h2;
      const short8 pa = *(const short8*)&p_lds[pb][h][lrow][lgrp << 3];
#pragma unroll
      for (int nh = 0; nh < 2; ++nh) {
        const short8 vb = *(const short8*)&v_t[((((size_t)((b << 3) + h) << 5) + (nh << 4) + lrow) << 10) + j0 + (lgrp << 3)];
        o_acc[h2][nh] = __builtin_amdgcn_mfma_f32_16x16x32_bf16(pa, vb, o_acc[h2][nh], 0, 0, 0);
      }
    }
  };

  constexpr int CHUNK = 1024 / JS;   // 256
  constexpr int NT = CHUNK / 32;     // 8 (even)
  const int jbeg = js * CHUNK;
  const int jlast = jbeg + CHUNK - 32;

  unsigned int ubA[2][4], ubB[2][4];
  LOADE(jbeg, ubA);
#pragma unroll 1
  for (int t2 = 0; t2 < NT; t2 += 2) {
    const int j0 = jbeg + (t2 << 5);
    const int jn1 = (j0 + 32 < jlast) ? (j0 + 32) : jlast;
    const int jn2 = (j0 + 64 < jlast) ? (j0 + 64) : jlast;
    LOADE(jn1, ubB);        // prefetch tile t2+1
    COMPUTE(j0, ubA, 0);
    LOADE(jn2, ubA);        // prefetch tile t2+2
    COMPUTE(j0 + 32, ubB, 1);
  }

  // ---- epilogue ----
#pragma unroll
  for (int h2 = 0; h2 < 2; ++h2) {
#pragma unroll
    for (int r = 0; r < 4; ++r) {
      float v = ls[h2][r];
      v += __shfl_xor(v, 1, 16);
      v += __shfl_xor(v, 2, 16);
      v += __shfl_xor(v, 4, 16);
      v += __shfl_xor(v, 8, 16);
      ls[h2][r] = v;
    }
  }
  const size_t obase = ((size_t)js << 20) + (((size_t)(b << 10) + i0) << 8);
#pragma unroll
  for (int h2 = 0; h2 < 2; ++h2) {
    const int h = (w << 1) + h2;
#pragma unroll
    for (int nh = 0; nh < 2; ++nh) {
      const int d = (h << 5) + (nh << 4) + lrow;
#pragma unroll
      for (int r = 0; r < 4; ++r)
        o_part[obase + ((size_t)((lgrp << 2) + r) << 8) + d] = o_acc[h2][nh][r];
    }
  }
  if (lrow == 0) {
#pragma unroll
    for (int h2 = 0; h2 < 2; ++h2) {
      const int h = (w << 1) + h2;
      float* lp = lsum_part + (((size_t)((js << 5) + (b << 3) + h)) << 10) + i0;
#pragma unroll
      for (int r = 0; r < 4; ++r)
        lp[(lgrp << 2) + r] = ls[h2][r];
    }
  }
}

__global__ __launch_bounds__(256) void out_proj(
    const float* __restrict__ o_part, const float* __restrict__ lsum_part,
    const float* __restrict__ Wo, const float* __restrict__ bo,
    float* __restrict__ out)
{
  constexpr int JS = JS_FIXED;
  __shared__ float o_lds[8][256];
  const int t = threadIdx.x;
  const int r0 = blockIdx.x << 3;
  const int h = t >> 5;
  for (int rr = 0; rr < 8; ++rr) {
    const int r = r0 + rr;
    const int l = r >> 2, bb = r & 3;
    const size_t base = (((size_t)(bb << 10) + l) << 8) + t;
    float acc = 0.f;
#pragma unroll
    for (int js = 0; js < JS; ++js)
      acc += o_part[((size_t)js << 20) + base];
    float lsv = 0.f;
#pragma unroll
    for (int js = 0; js < JS; ++js)
      lsv += lsum_part[(((size_t)((js << 5) + (bb << 3) + h)) << 10) + l];
    o_lds[rr][t] = acc / lsv;
  }
  __syncthreads();
  float accs[8];
#pragma unroll
  for (int rr = 0; rr < 8; ++rr) accs[rr] = 0.f;
  for (int k = 0; k < 256; ++k) {
    const float wo = Wo[k * 256 + t];
#pragma unroll
    for (int rr = 0; rr < 8; ++rr)
      accs[rr] = fmaf(o_lds[rr][k], wo, accs[rr]);
  }
  const float bov = bo[t];
#pragma unroll
  for (int rr = 0; rr < 8; ++rr)
    out[(size_t)(r0 + rr) * 256 + t] = accs[rr] + bov;
}

extern "C" void kernel_launch(void* const* d_in, const int* in_sizes, int n_in,
                              void* d_out, int out_size, void* d_ws, size_t ws_size,
                              hipStream_t stream)
{
  const float* s   = (const float*)d_in[0];
  const float* p   = (const float*)d_in[3];
  const float* Wq  = (const float*)d_in[4];
  const float* Wk  = (const float*)d_in[5];
  const float* Wv  = (const float*)d_in[6];
  const float* Wo  = (const float*)d_in[7];
  const float* bo  = (const float*)d_in[8];
  const float* W2d = (const float*)d_in[9];
  const float* b2d = (const float*)d_in[10];
  float* out = (float*)d_out;

  ushort_t* q_bf = (ushort_t*)d_ws;
  ushort_t* k_bf = q_bf + (1 << 20);
  ushort_t* v_t  = k_bf + (1 << 20);
  unsigned int* e16 = (unsigned int*)(v_t + (1 << 20));   // 16 planes * 1M uints = 64MiB
  float* o_part = (float*)((char*)e16 + ((size_t)1 << 26));
  float* lsum_part = o_part + ((size_t)JS_FIXED << 20);
  // total: 6MiB + 64MiB + 16MiB + 0.5MiB = 86.5MiB

  prep<<<dim3(512 + 16384), dim3(256), 0, stream>>>(s, Wq, Wk, Wv, p, W2d, b2d,
                                                    q_bf, k_bf, v_t, e16);
  attn_mfma<JS_FIXED><<<dim3(64, 4, JS_FIXED), dim3(256), 0, stream>>>(
      q_bf, k_bf, v_t, e16, o_part, lsum_part);
  out_proj<<<dim3(512), dim3(256), 0, stream>>>(o_part, lsum_part, Wo, bo, out);
}

// Round 11
// 142.177 us; speedup vs baseline: 1.8426x; 1.0069x over previous
//
#include <hip/hip_runtime.h>

// L=1024, B=4, IN=D=256, H=8, HD=32, IN2D=16
// ws (2B units): q_bf[1M] k_bf[1M] v_t[1M] | e16[32M halves, layout [b][w][i][j][2]]
// then (floats): o_part[JS*1M] lsum_part[JS*32K]

typedef __attribute__((ext_vector_type(8))) short short8;
typedef __attribute__((ext_vector_type(4))) float f32x4;
typedef __attribute__((ext_vector_type(2))) _Float16 half2_t;
typedef unsigned short ushort_t;

#define JS_FIXED 4

__device__ inline unsigned short f2bf(float f) {
  unsigned int u = __float_as_uint(f);
  return (unsigned short)((u + 0x7FFFu + ((u >> 16) & 1u)) >> 16);
}

// prep: blocks 0..511 do the QKV projection; blocks 512.. do the bias MLP.
// The VALU-bound qkv blocks co-schedule under the BW-bound bias stream.
__global__ __launch_bounds__(256) void prep(
    const float* __restrict__ s, const float* __restrict__ Wq,
    const float* __restrict__ Wk, const float* __restrict__ Wv,
    const float* __restrict__ p, const float* __restrict__ W2d,
    const float* __restrict__ b2d,
    ushort_t* __restrict__ q_bf, ushort_t* __restrict__ k_bf, ushort_t* __restrict__ v_t,
    unsigned int* __restrict__ e16)
{
  __shared__ float s_lds[8][256];
  __shared__ __align__(16) float w2d_s[128];
  __shared__ float b2d_s[8];
  const int t = threadIdx.x;

  if (blockIdx.x < 512) {
    // ---------------- QKV projection ----------------
    const int b = blockIdx.x >> 7;          // fixed batch per block
    const int l0 = (blockIdx.x & 127) << 3; // 8 consecutive l
    for (int rr = 0; rr < 8; ++rr)
      s_lds[rr][t] = s[((size_t)(((l0 + rr) << 2) + b) << 8) + t];
    __syncthreads();
    float aq[8], ak[8], av[8];
#pragma unroll
    for (int rr = 0; rr < 8; ++rr) { aq[rr] = 0.f; ak[rr] = 0.f; av[rr] = 0.f; }
    for (int k = 0; k < 256; ++k) {
      const float wq = Wq[k * 256 + t];
      const float wk = Wk[k * 256 + t];
      const float wv = Wv[k * 256 + t];
#pragma unroll
      for (int rr = 0; rr < 8; ++rr) {
        const float sv = s_lds[rr][k];
        aq[rr] = fmaf(sv, wq, aq[rr]);
        ak[rr] = fmaf(sv, wk, ak[rr]);
        av[rr] = fmaf(sv, wv, av[rr]);
      }
    }
    const int h = t >> 5, dl = t & 31;
#pragma unroll
    for (int rr = 0; rr < 8; ++rr) {
      const int l = l0 + rr;
      q_bf[(((size_t)(b << 10) + l) << 8) + t] = f2bf(aq[rr] * 0.0625f);
      k_bf[((((size_t)((b << 3) + h) << 10) + l) << 5) + dl] = f2bf(ak[rr]);
    }
    short8 vv;
#pragma unroll
    for (int rr = 0; rr < 8; ++rr) vv[rr] = (short)f2bf(av[rr]);
    *(short8*)&v_t[((((size_t)((b << 3) + h) << 5) + dl) << 10) + l0] = vv;
  } else {
    // ---------------- bias MLP (pure streaming) ----------------
    if (t < 128) w2d_s[t] = W2d[t];
    if (t < 8) b2d_s[t] = b2d[t];
    __syncthreads();
    const size_t n = (((size_t)blockIdx.x - 512) << 8) + t;  // 0 .. 4M-1
    const int b = (int)(n >> 20);
    const unsigned int ij = (unsigned int)(n & 0xFFFFFu);
    const float4* p4 = (const float4*)(p + (n << 4));
    const float4 a = p4[0], bb = p4[1], c = p4[2], d = p4[3];
    const float4* w4 = (const float4*)w2d_s;
    float acc[8];
#pragma unroll
    for (int h = 0; h < 8; ++h) {
      const float4 w0 = w4[h * 4 + 0], w1 = w4[h * 4 + 1];
      const float4 w2 = w4[h * 4 + 2], w3 = w4[h * 4 + 3];
      float av = b2d_s[h];
      av += a.x * w0.x + a.y * w0.y + a.z * w0.z + a.w * w0.w;
      av += bb.x * w1.x + bb.y * w1.y + bb.z * w1.z + bb.w * w1.w;
      av += c.x * w2.x + c.y * w2.y + c.z * w2.z + c.w * w2.w;
      av += d.x * w3.x + d.y * w3.y + d.z * w3.z + d.w * w3.w;
      acc[h] = av;
    }
    // per-head-pair planes: e16[((b*4+w)<<20) + ij] = half2(acc[2w], acc[2w+1])
#pragma unroll
    for (int w = 0; w < 4; ++w) {
      half2_t hv;
      hv[0] = (_Float16)acc[2 * w];
      hv[1] = (_Float16)acc[2 * w + 1];
      e16[(((size_t)((b << 2) + w)) << 20) + ij] = __builtin_bit_cast(unsigned int, hv);
    }
  }
}

template <int JS>
__global__ __launch_bounds__(256, 4) void attn_mfma(
    const ushort_t* __restrict__ q_bf, const ushort_t* __restrict__ k_bf,
    const ushort_t* __restrict__ v_t, const unsigned int* __restrict__ ep,
    float* __restrict__ o_part, float* __restrict__ lsum_part)
{
  __shared__ __align__(16) ushort_t p_lds[2][8][16][40];  // parity double-buffered

  const int t = threadIdx.x;
  // ---- bijective XCD swizzle: all js/b of an i-column family share an XCD L2 ----
  const int flat = blockIdx.x + (blockIdx.y << 6) + (blockIdx.z << 8);  // 0..1023
  const int swz = ((flat & 7) << 7) + (flat >> 3);
  const int i0 = (swz & 63) << 4;
  const int b  = (swz >> 6) & 3;
  const int js = swz >> 8;

  const int w = t >> 6;      // wave -> heads 2w, 2w+1
  const int l = t & 63;
  const int lrow = l & 15;
  const int lgrp = l >> 4;

  short8 qa[2];
#pragma unroll
  for (int h2 = 0; h2 < 2; ++h2) {
    const int h = (w << 1) + h2;
    qa[h2] = *(const short8*)&q_bf[(((size_t)(b << 10) + i0 + lrow) << 8) + (h << 5) + (lgrp << 3)];
  }

  f32x4 o_acc[2][2];
  float ls[2][4];
#pragma unroll
  for (int h2 = 0; h2 < 2; ++h2) {
#pragma unroll
    for (int nh = 0; nh < 2; ++nh) o_acc[h2][nh] = (f32x4){0.f, 0.f, 0.f, 0.f};
#pragma unroll
    for (int r = 0; r < 4; ++r) ls[h2][r] = 0.f;
  }

  // e16 plane [b][w]: fully-coalesced reads (lane stride 4B)
  const size_t A0 = (((size_t)((b << 2) + w)) << 20) + ((size_t)(i0 + (lgrp << 2)) << 10) + lrow;

  auto LOADE = [&](int j0, unsigned int (&ub)[2][4]) {
#pragma unroll
    for (int jh = 0; jh < 2; ++jh)
#pragma unroll
      for (int r = 0; r < 4; ++r)
        ub[jh][r] = ep[A0 + ((size_t)r << 10) + (jh << 4) + j0];
  };

  auto COMPUTE = [&](int j0, unsigned int (&ub)[2][4], int pb) {
    // ---- Scores: D = Q*K^T + bias(C), exp in-register, P -> bf16 LDS ----
#pragma unroll
    for (int jh = 0; jh < 2; ++jh) {
#pragma unroll
      for (int h2 = 0; h2 < 2; ++h2) {
        const int h = (w << 1) + h2;
        const short8 kb = *(const short8*)&k_bf[((((size_t)((b << 3) + h) << 10) + j0 + (jh << 4) + lrow) << 5) + (lgrp << 3)];
        f32x4 cc;
#pragma unroll
        for (int r = 0; r < 4; ++r) {
          const half2_t hv = __builtin_bit_cast(half2_t, ub[jh][r]);
          cc[r] = (float)hv[h2];
        }
        f32x4 d = __builtin_amdgcn_mfma_f32_16x16x32_bf16(qa[h2], kb, cc, 0, 0, 0);
#pragma unroll
        for (int r = 0; r < 4; ++r) {
          const float ex = __expf(d[r]);
          ls[h2][r] += ex;
          p_lds[pb][h][(lgrp << 2) + r][(jh << 4) + lrow] = f2bf(ex);
        }
      }
    }
    // ---- PV: o += P * V; P from wave-local LDS (A-frag), V JIT from L2 (B-frag) ----
#pragma unroll
    for (int h2 = 0; h2 < 2; ++h2) {
      const int h = (w << 1) + h2;
      const short8 pa = *(const short8*)&p_lds[pb][h][lrow][lgrp << 3];
#pragma unroll
      for (int nh = 0; nh < 2; ++nh) {
        const short8 vb = *(const short8*)&v_t[((((size_t)((b << 3) + h) << 5) + (nh << 4) + lrow) << 10) + j0 + (lgrp << 3)];
        o_acc[h2][nh] = __builtin_amdgcn_mfma_f32_16x16x32_bf16(pa, vb, o_acc[h2][nh], 0, 0, 0);
      }
    }
  };

  constexpr int CHUNK = 1024 / JS;   // 256
  constexpr int NT = CHUNK / 32;     // 8 (even)
  const int jbeg = js * CHUNK;
  const int jlast = jbeg + CHUNK - 32;

  unsigned int ubA[2][4], ubB[2][4];
  LOADE(jbeg, ubA);
#pragma unroll 1
  for (int t2 = 0; t2 < NT; t2 += 2) {
    const int j0 = jbeg + (t2 << 5);
    const int jn1 = (j0 + 32 < jlast) ? (j0 + 32) : jlast;
    const int jn2 = (j0 + 64 < jlast) ? (j0 + 64) : jlast;
    LOADE(jn1, ubB);        // prefetch tile t2+1
    COMPUTE(j0, ubA, 0);
    LOADE(jn2, ubA);        // prefetch tile t2+2
    COMPUTE(j0 + 32, ubB, 1);
  }

  // ---- epilogue ----
#pragma unroll
  for (int h2 = 0; h2 < 2; ++h2) {
#pragma unroll
    for (int r = 0; r < 4; ++r) {
      float v = ls[h2][r];
      v += __shfl_xor(v, 1, 16);
      v += __shfl_xor(v, 2, 16);
      v += __shfl_xor(v, 4, 16);
      v += __shfl_xor(v, 8, 16);
      ls[h2][r] = v;
    }
  }
  const size_t obase = ((size_t)js << 20) + (((size_t)(b << 10) + i0) << 8);
#pragma unroll
  for (int h2 = 0; h2 < 2; ++h2) {
    const int h = (w << 1) + h2;
#pragma unroll
    for (int nh = 0; nh < 2; ++nh) {
      const int d = (h << 5) + (nh << 4) + lrow;
#pragma unroll
      for (int r = 0; r < 4; ++r)
        o_part[obase + ((size_t)((lgrp << 2) + r) << 8) + d] = o_acc[h2][nh][r];
    }
  }
  if (lrow == 0) {
#pragma unroll
    for (int h2 = 0; h2 < 2; ++h2) {
      const int h = (w << 1) + h2;
      float* lp = lsum_part + (((size_t)((js << 5) + (b << 3) + h)) << 10) + i0;
#pragma unroll
      for (int r = 0; r < 4; ++r)
        lp[(lgrp << 2) + r] = ls[h2][r];
    }
  }
}

__global__ __launch_bounds__(256) void out_proj(
    const float* __restrict__ o_part, const float* __restrict__ lsum_part,
    const float* __restrict__ Wo, const float* __restrict__ bo,
    float* __restrict__ out)
{
  constexpr int JS = JS_FIXED;
  __shared__ float o_lds[8][256];
  const int t = threadIdx.x;
  const int r0 = blockIdx.x << 3;
  const int h = t >> 5;
  for (int rr = 0; rr < 8; ++rr) {
    const int r = r0 + rr;
    const int l = r >> 2, bb = r & 3;
    const size_t base = (((size_t)(bb << 10) + l) << 8) + t;
    float acc = 0.f;
#pragma unroll
    for (int js = 0; js < JS; ++js)
      acc += o_part[((size_t)js << 20) + base];
    float lsv = 0.f;
#pragma unroll
    for (int js = 0; js < JS; ++js)
      lsv += lsum_part[(((size_t)((js << 5) + (bb << 3) + h)) << 10) + l];
    o_lds[rr][t] = acc / lsv;
  }
  __syncthreads();
  float accs[8];
#pragma unroll
  for (int rr = 0; rr < 8; ++rr) accs[rr] = 0.f;
  for (int k = 0; k < 256; ++k) {
    const float wo = Wo[k * 256 + t];
#pragma unroll
    for (int rr = 0; rr < 8; ++rr)
      accs[rr] = fmaf(o_lds[rr][k], wo, accs[rr]);
  }
  const float bov = bo[t];
#pragma unroll
  for (int rr = 0; rr < 8; ++rr)
    out[(size_t)(r0 + rr) * 256 + t] = accs[rr] + bov;
}

extern "C" void kernel_launch(void* const* d_in, const int* in_sizes, int n_in,
                              void* d_out, int out_size, void* d_ws, size_t ws_size,
                              hipStream_t stream)
{
  const float* s   = (const float*)d_in[0];
  const float* p   = (const float*)d_in[3];
  const float* Wq  = (const float*)d_in[4];
  const float* Wk  = (const float*)d_in[5];
  const float* Wv  = (const float*)d_in[6];
  const float* Wo  = (const float*)d_in[7];
  const float* bo  = (const float*)d_in[8];
  const float* W2d = (const float*)d_in[9];
  const float* b2d = (const float*)d_in[10];
  float* out = (float*)d_out;

  ushort_t* q_bf = (ushort_t*)d_ws;
  ushort_t* k_bf = q_bf + (1 << 20);
  ushort_t* v_t  = k_bf + (1 << 20);
  unsigned int* e16 = (unsigned int*)(v_t + (1 << 20));   // 16 planes * 1M uints = 64MiB
  float* o_part = (float*)((char*)e16 + ((size_t)1 << 26));
  float* lsum_part = o_part + ((size_t)JS_FIXED << 20);
  // total: 6MiB + 64MiB + 16MiB + 0.5MiB = 86.5MiB

  prep<<<dim3(512 + 16384), dim3(256), 0, stream>>>(s, Wq, Wk, Wv, p, W2d, b2d,
                                                    q_bf, k_bf, v_t, e16);
  attn_mfma<JS_FIXED><<<dim3(64, 4, JS_FIXED), dim3(256), 0, stream>>>(
      q_bf, k_bf, v_t, e16, o_part, lsum_part);
  out_proj<<<dim3(512), dim3(256), 0, stream>>>(o_part, lsum_part, Wo, bo, out);
}